// Round 1
// baseline (78.178 us; speedup 1.0000x reference)
//
#include <hip/hip_runtime.h>
#include <hip/hip_bf16.h>

// out[b,c] = dot(x[b,c,:], W[c,:]) + bias[c]
// B=256, C=512, D=784 (=28*28). x rows are contiguous [B*C][D] f32.
// One 64-lane wave per output element. Memory-bound: ~411 MB of x, floor ~65us.

#define B_ 256
#define C_ 512
#define D_ 784
#define D4 (D_ / 4)   // 196 float4 per row

__global__ __launch_bounds__(256) void dot_rows_kernel(
    const float* __restrict__ x,
    const float* __restrict__ W,
    const float* __restrict__ bias,
    float* __restrict__ out)
{
    const int wave = (int)((blockIdx.x * (unsigned)blockDim.x + threadIdx.x) >> 6);
    const int lane = threadIdx.x & 63;
    if (wave >= B_ * C_) return;

    const int c = wave & (C_ - 1);            // C=512 is power of 2

    const float4* __restrict__ xr = reinterpret_cast<const float4*>(x + (size_t)wave * D_);
    const float4* __restrict__ wr = reinterpret_cast<const float4*>(W + (size_t)c * D_);

    float sum = 0.0f;
    // 196 float4 per row; lanes 0..63 stride by 64: 3 iters each, lanes 0..3 get a 4th.
    #pragma unroll
    for (int i = lane; i < D4; i += 64) {
        float4 xv = xr[i];
        float4 wv = wr[i];
        sum += xv.x * wv.x + xv.y * wv.y + xv.z * wv.z + xv.w * wv.w;
    }

    // 64-lane wave reduction (CDNA wave = 64, not 32)
    #pragma unroll
    for (int off = 32; off > 0; off >>= 1)
        sum += __shfl_down(sum, off, 64);

    if (lane == 0)
        out[wave] = sum + bias[c];
}

extern "C" void kernel_launch(void* const* d_in, const int* in_sizes, int n_in,
                              void* d_out, int out_size, void* d_ws, size_t ws_size,
                              hipStream_t stream) {
    const float* x    = (const float*)d_in[0];   // [B, C, H, W] = [B*C, D]
    const float* W    = (const float*)d_in[1];   // [C, D]
    const float* bias = (const float*)d_in[2];   // [C]
    float* out        = (float*)d_out;           // [B, C, 1] = B*C floats

    const int total_waves = B_ * C_;             // 131072
    const int waves_per_block = 256 / 64;        // 4
    const int grid = total_waves / waves_per_block;  // 32768

    dot_rows_kernel<<<grid, 256, 0, stream>>>(x, W, bias, out);
}

// Round 3
// 65.472 us; speedup vs baseline: 1.1941x; 1.1941x over previous
//
#include <hip/hip_runtime.h>
#include <hip/hip_bf16.h>

// out[b,c] = dot(x[b,c,:], W[c,:]) + bias[c];  B=256, C=512, D=784.
// One 64-lane wave per (channel c, group of R_ batch rows):
//   - W[c] register-cached once per wave (196 float4 spread over 64 lanes)
//   - loop over R_ = 8 batch rows, x via nontemporal 16B vector loads (no reuse)
//   - 8 wave reductions + lane-0 stores.
// Memory-bound: ~411 MB compulsory x read; target ~6.3+ TB/s (~62 us).

#define B_ 256
#define C_ 512
#define D_ 784
#define D4 196      // float4 per row
#define R_ 8        // batch rows per wave

typedef float f32x4 __attribute__((ext_vector_type(4)));  // native vector: OK for nontemporal builtins

__global__ __launch_bounds__(256) void dot_rows_kernel(
    const float* __restrict__ x,
    const float* __restrict__ W,
    const float* __restrict__ bias,
    float* __restrict__ out)
{
    const int wid  = (int)(blockIdx.x * 4u + (threadIdx.x >> 6));
    const int lane = threadIdx.x & 63;

    const int c  = wid & (C_ - 1);        // consecutive waves -> consecutive c (contiguous x rows)
    const int b0 = (wid >> 9) * R_;       // 512 channels per b-group

    // Register-cache W[c]: lane holds float4 indices {lane, lane+64, lane+128, (+192 lanes 0..3)}
    const f32x4* __restrict__ wr = reinterpret_cast<const f32x4*>(W + (size_t)c * D_);
    const f32x4 w0 = wr[lane];
    const f32x4 w1 = wr[lane + 64];
    const f32x4 w2 = wr[lane + 128];
    f32x4 w3 = (f32x4)(0.f);
    if (lane < (D4 - 192)) w3 = wr[lane + 192];

    float s[R_];
    #pragma unroll
    for (int r = 0; r < R_; ++r) {
        const f32x4* __restrict__ xr =
            reinterpret_cast<const f32x4*>(x + ((size_t)(b0 + r) * C_ + c) * D_);
        const f32x4 x0 = __builtin_nontemporal_load(xr + lane);
        const f32x4 x1 = __builtin_nontemporal_load(xr + lane + 64);
        const f32x4 x2 = __builtin_nontemporal_load(xr + lane + 128);
        f32x4 x3 = (f32x4)(0.f);
        if (lane < (D4 - 192)) x3 = __builtin_nontemporal_load(xr + lane + 192);

        float acc;
        acc  = x0.x * w0.x + x0.y * w0.y + x0.z * w0.z + x0.w * w0.w;
        acc += x1.x * w1.x + x1.y * w1.y + x1.z * w1.z + x1.w * w1.w;
        acc += x2.x * w2.x + x2.y * w2.y + x2.z * w2.z + x2.w * w2.w;
        acc += x3.x * w3.x + x3.y * w3.y + x3.z * w3.z + x3.w * w3.w;
        s[r] = acc;
    }

    // 64-lane wave reductions (independent chains pipeline across r)
    #pragma unroll
    for (int r = 0; r < R_; ++r) {
        float v = s[r];
        #pragma unroll
        for (int off = 32; off > 0; off >>= 1)
            v += __shfl_down(v, off, 64);
        s[r] = v;
    }

    if (lane == 0) {
        const float bc = bias[c];
        #pragma unroll
        for (int r = 0; r < R_; ++r)
            out[(size_t)(b0 + r) * C_ + c] = s[r] + bc;
    }
}

extern "C" void kernel_launch(void* const* d_in, const int* in_sizes, int n_in,
                              void* d_out, int out_size, void* d_ws, size_t ws_size,
                              hipStream_t stream) {
    const float* x    = (const float*)d_in[0];   // [B, C, H, W] = [B*C, D]
    const float* W    = (const float*)d_in[1];   // [C, D]
    const float* bias = (const float*)d_in[2];   // [C]
    float* out        = (float*)d_out;           // [B*C] floats

    const int total_waves = (B_ / R_) * C_;      // 16384
    const int grid = total_waves / 4;            // 4 waves per 256-thread block -> 4096

    dot_rows_kernel<<<grid, 256, 0, stream>>>(x, W, bias, out);
}